// Round 1
// baseline (2101.332 us; speedup 1.0000x reference)
//
#include <hip/hip_runtime.h>

// ODE-GRU recurrence, B=128, L=2048, I=D=64.
// One block per batch (128 blocks, 256 threads = 4 waves).
// Strictly sequential over L; all weights register-resident; dots K-split x4
// over lane-quads with shfl_xor reduction; h/t1/h_ode/gh/gx through LDS;
// outputs tile-buffered in LDS to keep global-store drains off the step
// critical path.

#define NB    128
#define SEQ   2048
#define DIM   64
#define TILE  64

__device__ __forceinline__ float fast_rcp(float x) { return __builtin_amdgcn_rcpf(x); }

__device__ __forceinline__ float sigmoid_f(float v) {
    // 1/(1+e^-v); __expf -> v_exp_f32, rcp ~1ulp. Safe at +-inf.
    return fast_rcp(1.0f + __expf(-v));
}
__device__ __forceinline__ float tanh_f(float v) {
    // 1 - 2/(e^{2v}+1): safe form (no inf/inf NaN when e overflows).
    float e = __expf(2.0f * v);
    return fmaf(-2.0f, fast_rcp(e + 1.0f), 1.0f);
}

__global__ __launch_bounds__(256, 1)
void odegru_fused(const float* __restrict__ x,        // (B,L,I)
                  const float* __restrict__ tds,      // (B,L)
                  const int*   __restrict__ seq_lens, // (B)
                  const float* __restrict__ h0,       // (D)
                  const float* __restrict__ w_ih,     // (3D,I)
                  const float* __restrict__ w_hh,     // (3D,D)
                  const float* __restrict__ b_ih,     // (3D)
                  const float* __restrict__ b_hh,     // (3D)
                  const float* __restrict__ dw1,      // (D,D)
                  const float* __restrict__ db1,      // (D)
                  const float* __restrict__ dw2,      // (D,D)
                  const float* __restrict__ db2,      // (D)
                  float* __restrict__ out)            // (B,L,D) ++ (B,D)
{
    const int b   = blockIdx.x;
    const int tid = threadIdx.x;
    const int q   = tid >> 2;   // quad 0..63: owns output row(s)
    const int p   = tid & 3;    // lane in quad: K-range [16p,16p+16)
    const int seqlen = seq_lens[b];

    __shared__ float sh_h [DIM];
    __shared__ float sh_t1[DIM];
    __shared__ float sh_ho[DIM];
    __shared__ float sh_gh[3*DIM];
    __shared__ float sh_gx[3*DIM];
    __shared__ float sh_x [TILE][DIM];
    __shared__ float sh_dt[TILE];
    __shared__ float sh_out[TILE][DIM];

    // ---- weights -> registers (one-time). dw1/dw2: row q, chunk p.
    //      w_hh/w_ih: rows 3q..3q+2, chunk p.  128 float regs/thread.
    float4 wa[4], wb[4], wg[3][4], wx[3][4];
    {
        const float4* dw1v = (const float4*)dw1;
        const float4* dw2v = (const float4*)dw2;
        const float4* whhv = (const float4*)w_hh;
        const float4* wihv = (const float4*)w_ih;
        const int base = q * 16 + p * 4;   // float4 idx: row q (16 f4/row) + chunk
#pragma unroll
        for (int i = 0; i < 4; i++) wa[i] = dw1v[base + i];
#pragma unroll
        for (int i = 0; i < 4; i++) wb[i] = dw2v[base + i];
#pragma unroll
        for (int r = 0; r < 3; r++) {
            const int rb = (3 * q + r) * 16 + p * 4;
#pragma unroll
            for (int i = 0; i < 4; i++) { wg[r][i] = whhv[rb + i]; wx[r][i] = wihv[rb + i]; }
        }
    }
    const float rdb1 = db1[q], rdb2 = db2[q];
    const float rbh0 = b_hh[3*q], rbh1 = b_hh[3*q+1], rbh2 = b_hh[3*q+2];
    const float rbx0 = b_ih[3*q], rbx1 = b_ih[3*q+1], rbx2 = b_ih[3*q+2];

    if (tid < DIM) sh_h[tid] = h0[tid];   // h_init broadcast of h0

    const float* xb  = x   + (size_t)b * SEQ * DIM;
    const float* tdb = tds + (size_t)b * SEQ;
    float* outb = out + (size_t)b * SEQ * DIM;
    float* finb = out + (size_t)NB * SEQ * DIM + (size_t)b * DIM;

    for (int t0 = 0; t0 < SEQ; t0 += TILE) {
        // ---- stage x tile (masked: x=0 for t>=seqlen) + dt tile (masked) ----
        {
            const float4* src = (const float4*)(xb + (size_t)t0 * DIM);
            float4* dst = (float4*)(&sh_x[0][0]);
#pragma unroll
            for (int i = 0; i < TILE * DIM / 4; i += 256) {
                const int idx = i + tid;
                float4 v = src[idx];
                const int t = t0 + (idx >> 4);         // 16 float4 per row
                if (t >= seqlen) v = make_float4(0.f, 0.f, 0.f, 0.f);
                dst[idx] = v;
            }
            if (tid < TILE) {
                const int t = t0 + tid;
                sh_dt[tid] = (t < seqlen) ? tdb[t] : 0.0f;
            }
        }
        __syncthreads();

#pragma unroll 1
        for (int ts = 0; ts < TILE; ts++) {
            const int t = t0 + ts;

            // ---- Phase A: t1 = tanh(dw1 @ h + db1) ----
            {
                const float4* hv = (const float4*)sh_h;
                float acc = 0.f;
#pragma unroll
                for (int i = 0; i < 4; i++) {
                    const float4 h4 = hv[p * 4 + i];
                    acc = fmaf(wa[i].x, h4.x, acc);
                    acc = fmaf(wa[i].y, h4.y, acc);
                    acc = fmaf(wa[i].z, h4.z, acc);
                    acc = fmaf(wa[i].w, h4.w, acc);
                }
                acc += __shfl_xor(acc, 1);
                acc += __shfl_xor(acc, 2);
                if (p == 0) sh_t1[q] = tanh_f(acc + rdb1);
            }
            __syncthreads();

            // ---- Phase B: h_ode = h + (dw2 @ t1 + db2) * dt ----
            {
                const float4* tv = (const float4*)sh_t1;
                float acc = 0.f;
#pragma unroll
                for (int i = 0; i < 4; i++) {
                    const float4 t4 = tv[p * 4 + i];
                    acc = fmaf(wb[i].x, t4.x, acc);
                    acc = fmaf(wb[i].y, t4.y, acc);
                    acc = fmaf(wb[i].z, t4.z, acc);
                    acc = fmaf(wb[i].w, t4.w, acc);
                }
                acc += __shfl_xor(acc, 1);
                acc += __shfl_xor(acc, 2);
                if (p == 0) sh_ho[q] = fmaf(acc + rdb2, sh_dt[ts], sh_h[q]);
            }
            __syncthreads();

            // ---- Phase C: gh = w_hh @ h_ode + b_hh; gx = w_ih @ x_t + b_ih
            //      quad q owns global rows 3q..3q+2 of both ----
            {
                const float4* hov = (const float4*)sh_ho;
                const float4* xv  = (const float4*)(&sh_x[ts][0]);
                float g0 = 0.f, g1 = 0.f, g2 = 0.f, e0 = 0.f, e1 = 0.f, e2 = 0.f;
#pragma unroll
                for (int i = 0; i < 4; i++) {
                    const float4 h4 = hov[p * 4 + i];
                    const float4 x4 = xv [p * 4 + i];
                    g0 = fmaf(wg[0][i].x, h4.x, g0); g0 = fmaf(wg[0][i].y, h4.y, g0);
                    g0 = fmaf(wg[0][i].z, h4.z, g0); g0 = fmaf(wg[0][i].w, h4.w, g0);
                    g1 = fmaf(wg[1][i].x, h4.x, g1); g1 = fmaf(wg[1][i].y, h4.y, g1);
                    g1 = fmaf(wg[1][i].z, h4.z, g1); g1 = fmaf(wg[1][i].w, h4.w, g1);
                    g2 = fmaf(wg[2][i].x, h4.x, g2); g2 = fmaf(wg[2][i].y, h4.y, g2);
                    g2 = fmaf(wg[2][i].z, h4.z, g2); g2 = fmaf(wg[2][i].w, h4.w, g2);
                    e0 = fmaf(wx[0][i].x, x4.x, e0); e0 = fmaf(wx[0][i].y, x4.y, e0);
                    e0 = fmaf(wx[0][i].z, x4.z, e0); e0 = fmaf(wx[0][i].w, x4.w, e0);
                    e1 = fmaf(wx[1][i].x, x4.x, e1); e1 = fmaf(wx[1][i].y, x4.y, e1);
                    e1 = fmaf(wx[1][i].z, x4.z, e1); e1 = fmaf(wx[1][i].w, x4.w, e1);
                    e2 = fmaf(wx[2][i].x, x4.x, e2); e2 = fmaf(wx[2][i].y, x4.y, e2);
                    e2 = fmaf(wx[2][i].z, x4.z, e2); e2 = fmaf(wx[2][i].w, x4.w, e2);
                }
                g0 += __shfl_xor(g0, 1); g0 += __shfl_xor(g0, 2);
                g1 += __shfl_xor(g1, 1); g1 += __shfl_xor(g1, 2);
                g2 += __shfl_xor(g2, 1); g2 += __shfl_xor(g2, 2);
                e0 += __shfl_xor(e0, 1); e0 += __shfl_xor(e0, 2);
                e1 += __shfl_xor(e1, 1); e1 += __shfl_xor(e1, 2);
                e2 += __shfl_xor(e2, 1); e2 += __shfl_xor(e2, 2);
                if (p == 0) {
                    sh_gh[3*q  ] = g0 + rbh0;
                    sh_gh[3*q+1] = g1 + rbh1;
                    sh_gh[3*q+2] = g2 + rbh2;
                    sh_gx[3*q  ] = e0 + rbx0;
                    sh_gx[3*q+1] = e1 + rbx1;
                    sh_gx[3*q+2] = e2 + rbx2;
                }
            }
            __syncthreads();

            // ---- Gates (wave 0): r,z,n -> h_new; buffer output in LDS ----
            if (tid < DIM) {
                const int j = tid;
                const float rg = sigmoid_f(sh_gx[j]        + sh_gh[j]);
                const float zg = sigmoid_f(sh_gx[DIM + j]  + sh_gh[DIM + j]);
                const float ng = tanh_f(fmaf(rg, sh_gh[2*DIM + j], sh_gx[2*DIM + j]));
                const float ho = sh_ho[j];
                const float hn = fmaf(zg, ho - ng, ng);   // (1-z)*n + z*ho
                sh_h[j] = hn;
                sh_out[ts][j] = hn;
                if (t == seqlen - 1) finb[j] = hn;        // final state (once/block)
            }
            __syncthreads();
        }

        // ---- flush output tile: coalesced float4 stores, one vm drain/tile ----
        {
            float4* dst = (float4*)(outb + (size_t)t0 * DIM);
            const float4* src = (const float4*)(&sh_out[0][0]);
#pragma unroll
            for (int i = 0; i < TILE * DIM / 4; i += 256) dst[i + tid] = src[i + tid];
        }
    }
}

extern "C" void kernel_launch(void* const* d_in, const int* in_sizes, int n_in,
                              void* d_out, int out_size, void* d_ws, size_t ws_size,
                              hipStream_t stream) {
    const float* x    = (const float*)d_in[0];
    const float* tds  = (const float*)d_in[1];
    const int*   sl   = (const int*)  d_in[2];
    const float* h0   = (const float*)d_in[3];
    const float* w_ih = (const float*)d_in[4];
    const float* w_hh = (const float*)d_in[5];
    const float* b_ih = (const float*)d_in[6];
    const float* b_hh = (const float*)d_in[7];
    const float* dw1  = (const float*)d_in[8];
    const float* db1  = (const float*)d_in[9];
    const float* dw2  = (const float*)d_in[10];
    const float* db2  = (const float*)d_in[11];
    float* out = (float*)d_out;

    odegru_fused<<<dim3(NB), dim3(256), 0, stream>>>(
        x, tds, sl, h0, w_ih, w_hh, b_ih, b_hh, dw1, db1, dw2, db2, out);
}

// Round 2
// 1845.094 us; speedup vs baseline: 1.1389x; 1.1389x over previous
//
#include <hip/hip_runtime.h>

// ODE-GRU recurrence, B=128, L=2048, I=D=64.
// One block per batch (128 blocks, 256 threads = 4 waves).
// R2 changes vs R1:
//  - DPP quad_perm butterflies (VALU) replace ds_swizzle shfl_xor (~300 cyc/step saved)
//  - quad q owns gate rows {q, 64+q, 128+q} -> gates fused into phase C
//    (4 barriers/step -> 3, no wave0-only gates phase)
//  - gx = w_ih@x+b_ih precomputed per 32-step tile into LDS (off critical path),
//    prefetched per step at phase-A start; per-thread persistent weights 128->80 floats
//  - 4 accumulators in phases A/B (serial fma chain 64 -> ~16 cyc)
//  - sh_x stride 68 / sh_gx stride 200 (bank-conflict-free)

#define NB    128
#define SEQ   2048
#define DIM   64
#define TILE  32
#define XS    68     // sh_x row stride (floats)
#define GS    200    // sh_gx row stride (floats)

__device__ __forceinline__ float fast_rcp(float x) { return __builtin_amdgcn_rcpf(x); }

__device__ __forceinline__ float sigmoid_f(float v) {
    return fast_rcp(1.0f + __expf(-v));
}
__device__ __forceinline__ float tanh_f(float v) {
    float e = __expf(2.0f * v);
    return fmaf(-2.0f, fast_rcp(e + 1.0f), 1.0f);
}

// Butterfly sum over a lane-quad; every lane of the quad gets the total.
// quad_perm [1,0,3,2] = 0xB1, [2,3,0,1] = 0x4E. VALU DPP — no LDS pipe.
__device__ __forceinline__ float quad_reduce(float v) {
    v += __int_as_float(__builtin_amdgcn_mov_dpp(__float_as_int(v), 0xB1, 0xF, 0xF, true));
    v += __int_as_float(__builtin_amdgcn_mov_dpp(__float_as_int(v), 0x4E, 0xF, 0xF, true));
    return v;
}

__device__ __forceinline__ float dot16(const float4* w, const float4* h) {
    float a0 = 0.f, a1 = 0.f, a2 = 0.f, a3 = 0.f;
    a0 = fmaf(w[0].x, h[0].x, a0); a0 = fmaf(w[0].y, h[0].y, a0);
    a0 = fmaf(w[0].z, h[0].z, a0); a0 = fmaf(w[0].w, h[0].w, a0);
    a1 = fmaf(w[1].x, h[1].x, a1); a1 = fmaf(w[1].y, h[1].y, a1);
    a1 = fmaf(w[1].z, h[1].z, a1); a1 = fmaf(w[1].w, h[1].w, a1);
    a2 = fmaf(w[2].x, h[2].x, a2); a2 = fmaf(w[2].y, h[2].y, a2);
    a2 = fmaf(w[2].z, h[2].z, a2); a2 = fmaf(w[2].w, h[2].w, a2);
    a3 = fmaf(w[3].x, h[3].x, a3); a3 = fmaf(w[3].y, h[3].y, a3);
    a3 = fmaf(w[3].z, h[3].z, a3); a3 = fmaf(w[3].w, h[3].w, a3);
    return (a0 + a1) + (a2 + a3);
}

__global__ __launch_bounds__(256, 1)
void odegru_fused(const float* __restrict__ x,        // (B,L,I)
                  const float* __restrict__ tds,      // (B,L)
                  const int*   __restrict__ seq_lens, // (B)
                  const float* __restrict__ h0,       // (D)
                  const float* __restrict__ w_ih,     // (3D,I)
                  const float* __restrict__ w_hh,     // (3D,D)
                  const float* __restrict__ b_ih,     // (3D)
                  const float* __restrict__ b_hh,     // (3D)
                  const float* __restrict__ dw1,      // (D,D)
                  const float* __restrict__ db1,      // (D)
                  const float* __restrict__ dw2,      // (D,D)
                  const float* __restrict__ db2,      // (D)
                  float* __restrict__ out)            // (B,L,D) ++ (B,D)
{
    const int b   = blockIdx.x;
    const int tid = threadIdx.x;
    const int q   = tid >> 2;   // quad 0..63: owns output element q
    const int p   = tid & 3;    // lane in quad: K-chunk [16p, 16p+16)
    const int seqlen = seq_lens[b];

    __shared__ float sh_h [DIM];
    __shared__ float sh_t1[DIM];
    __shared__ float sh_ho[DIM];
    __shared__ float sh_x [TILE][XS];
    __shared__ float sh_gx[TILE][GS];
    __shared__ float sh_dt[TILE];
    __shared__ float sh_out[TILE][DIM];

    // ---- persistent weights -> registers: 80 floats/thread ----
    // wa: dw1 row q, k-chunk p. wb: dw2 row q, chunk p.
    // wg[r]: w_hh row 64r+q (gate r of element q), chunk p.
    float4 wa[4], wb[4], wg[3][4];
    {
        const float4* dw1v = (const float4*)dw1;
        const float4* dw2v = (const float4*)dw2;
        const float4* whhv = (const float4*)w_hh;
        const int base = q * 16 + p * 4;
#pragma unroll
        for (int i = 0; i < 4; i++) wa[i] = dw1v[base + i];
#pragma unroll
        for (int i = 0; i < 4; i++) wb[i] = dw2v[base + i];
#pragma unroll
        for (int r = 0; r < 3; r++) {
            const int rb = (64 * r + q) * 16 + p * 4;
#pragma unroll
            for (int i = 0; i < 4; i++) wg[r][i] = whhv[rb + i];
        }
    }
    const float rdb1 = db1[q], rdb2 = db2[q];
    const float rbh0 = b_hh[q], rbh1 = b_hh[DIM + q], rbh2 = b_hh[2 * DIM + q];
    const float rbx0 = b_ih[q], rbx1 = b_ih[DIM + q], rbx2 = b_ih[2 * DIM + q];

    if (tid < DIM) sh_h[tid] = h0[tid];

    const float* xb  = x   + (size_t)b * SEQ * DIM;
    const float* tdb = tds + (size_t)b * SEQ;
    float* outb = out + (size_t)b * SEQ * DIM;
    float* finb = out + (size_t)NB * SEQ * DIM + (size_t)b * DIM;

    const float4* wihv = (const float4*)w_ih;

    for (int t0 = 0; t0 < SEQ; t0 += TILE) {
        // ---- stage x tile (masked) + dt tile (masked) ----
        {
            const float4* src = (const float4*)(xb + (size_t)t0 * DIM);
#pragma unroll
            for (int i = tid; i < TILE * 16; i += 256) {
                const int ts = i >> 4, j = i & 15;
                float4 v = src[i];
                if (t0 + ts >= seqlen) v = make_float4(0.f, 0.f, 0.f, 0.f);
                *(float4*)&sh_x[ts][4 * j] = v;
            }
            if (tid < TILE) {
                const int t = t0 + tid;
                sh_dt[tid] = (t < seqlen) ? tdb[t] : 0.0f;
            }
        }
        __syncthreads();

        // ---- gx tile: gx[ts][{q,64+q,128+q}] = w_ih rows @ x_ts + b_ih ----
        // k-split by p, quad_reduce; dense dependency-free compute.
        {
            float4 wi0[4], wi1[4], wi2[4];
            const int c = p * 4;
#pragma unroll
            for (int i = 0; i < 4; i++) {
                wi0[i] = wihv[(q)            * 16 + c + i];
                wi1[i] = wihv[(DIM + q)      * 16 + c + i];
                wi2[i] = wihv[(2 * DIM + q)  * 16 + c + i];
            }
#pragma unroll 4
            for (int ts = 0; ts < TILE; ts++) {
                const float4* xv = (const float4*)&sh_x[ts][0];
                float4 x4[4] = { xv[c], xv[c + 1], xv[c + 2], xv[c + 3] };
                float A0 = dot16(wi0, x4);
                float A1 = dot16(wi1, x4);
                float A2 = dot16(wi2, x4);
                A0 = quad_reduce(A0);
                A1 = quad_reduce(A1);
                A2 = quad_reduce(A2);
                if (p == 0) {
                    sh_gx[ts][q]           = A0 + rbx0;
                    sh_gx[ts][DIM + q]     = A1 + rbx1;
                    sh_gx[ts][2 * DIM + q] = A2 + rbx2;
                }
            }
        }
        __syncthreads();

#pragma unroll 1
        for (int ts = 0; ts < TILE; ts++) {
            const int t = t0 + ts;

            // ---- prefetch (independent LDS reads; hide under A+B) ----
            const float gx0 = sh_gx[ts][q];
            const float gx1 = sh_gx[ts][DIM + q];
            const float gx2 = sh_gx[ts][2 * DIM + q];
            const float hq  = sh_h[q];
            const float dtv = sh_dt[ts];

            // ---- Phase A: t1 = tanh(dw1 @ h + db1) ----
            {
                const float4* hv = (const float4*)sh_h;
                float4 h4[4] = { hv[p*4], hv[p*4+1], hv[p*4+2], hv[p*4+3] };
                float s = quad_reduce(dot16(wa, h4));
                if (p == 0) sh_t1[q] = tanh_f(s + rdb1);
            }
            __syncthreads();

            // ---- Phase B: h_ode = h + (dw2 @ t1 + db2) * dt ----
            float hoq;
            {
                const float4* tv = (const float4*)sh_t1;
                float4 t4[4] = { tv[p*4], tv[p*4+1], tv[p*4+2], tv[p*4+3] };
                float s = quad_reduce(dot16(wb, t4));
                hoq = fmaf(s + rdb2, dtv, hq);      // all 4 lanes have it
                if (p == 0) sh_ho[q] = hoq;
            }
            __syncthreads();

            // ---- Phase C + gates: gh rows {q,64+q,128+q}; h_new in-quad ----
            {
                const float4* hov = (const float4*)sh_ho;
                float4 h4[4] = { hov[p*4], hov[p*4+1], hov[p*4+2], hov[p*4+3] };
                float g0 = quad_reduce(dot16(wg[0], h4));
                float g1 = quad_reduce(dot16(wg[1], h4));
                float g2 = quad_reduce(dot16(wg[2], h4));
                const float rg = sigmoid_f(gx0 + g0 + rbh0);
                const float zg = sigmoid_f(gx1 + g1 + rbh1);
                const float ng = tanh_f(fmaf(rg, g2 + rbh2, gx2));
                const float hn = fmaf(zg, hoq - ng, ng);   // (1-z)*n + z*ho
                if (p == 0) {
                    sh_h[q] = hn;
                    sh_out[ts][q] = hn;
                    if (t == seqlen - 1) finb[q] = hn;
                }
            }
            __syncthreads();
        }

        // ---- flush output tile: coalesced float4 stores ----
        {
            float4* dst = (float4*)(outb + (size_t)t0 * DIM);
            const float4* src = (const float4*)(&sh_out[0][0]);
#pragma unroll
            for (int i = tid; i < TILE * DIM / 4; i += 256) dst[i] = src[i];
        }
    }
}

extern "C" void kernel_launch(void* const* d_in, const int* in_sizes, int n_in,
                              void* d_out, int out_size, void* d_ws, size_t ws_size,
                              hipStream_t stream) {
    const float* x    = (const float*)d_in[0];
    const float* tds  = (const float*)d_in[1];
    const int*   sl   = (const int*)  d_in[2];
    const float* h0   = (const float*)d_in[3];
    const float* w_ih = (const float*)d_in[4];
    const float* w_hh = (const float*)d_in[5];
    const float* b_ih = (const float*)d_in[6];
    const float* b_hh = (const float*)d_in[7];
    const float* dw1  = (const float*)d_in[8];
    const float* db1  = (const float*)d_in[9];
    const float* dw2  = (const float*)d_in[10];
    const float* db2  = (const float*)d_in[11];
    float* out = (float*)d_out;

    odegru_fused<<<dim3(NB), dim3(256), 0, stream>>>(
        x, tds, sl, h0, w_ih, w_hh, b_ih, b_hh, dw1, db1, dw2, db2, out);
}